// Round 8
// baseline (736.944 us; speedup 1.0000x reference)
//
#include <hip/hip_runtime.h>

// PhaMPN v8: T-space fused pipeline.
//   binput = fedges @ W_i (MFMA, bf16); msg1 = bf16(sigmoid(binput))
//   T1 = msg1 @ W_h                                  [k_mmul]
//   4x: T_{d+1} = bf16( sigmoid(binput + sum_8 T_d[egraph]) @ W_h )   [k_fused]
//   U  = bf16( sigmoid(binput + sum_8 T_5[egraph]) @ Wo_bot )         [k_fused]
//   F = features @ Wo_top + b_o;  hidden = bf16(sigmoid(F + sum_8 U[agraph]))
//   out = segment-mean(hidden).   (msg is never materialized after msg1.)

typedef __attribute__((ext_vector_type(4))) float f32x4;
typedef __attribute__((ext_vector_type(8))) short s16x8;
typedef unsigned short u16;

constexpr int Nn   = 50000;
constexpr int Ee   = 150000;
constexpr int NBn  = 8;
constexpr int Hh   = 128;
constexpr int FFn  = 40;
constexpr int Bm   = 500;
constexpr int KI   = 72;       // fedges/features tile stride (K padded -> 64)
constexpr int ACCW = 132;      // f32 acc stride (k_binput / k_fgemm)
constexpr int ACC2 = 130;      // f32 acc stride (k_mmul / k_fused)

__device__ __forceinline__ float sigmoidf_(float x) {
    return 1.0f / (1.0f + __expf(-x));
}
__device__ __forceinline__ u16 f2bf(float f) {
    unsigned u = __float_as_uint(f);
    u += 0x7fffu + ((u >> 16) & 1u);
    return (u16)(u >> 16);
}
__device__ __forceinline__ float bflo(unsigned u) { return __uint_as_float(u << 16); }
__device__ __forceinline__ float bfhi(unsigned u) { return __uint_as_float(u & 0xffff0000u); }
__device__ __forceinline__ float bf1(u16 h) { return __uint_as_float(((unsigned)h) << 16); }
__device__ __forceinline__ unsigned pack2(float x, float y) {
    return (unsigned)f2bf(x) | ((unsigned)f2bf(y) << 16);
}
__device__ __forceinline__ void add8(float* a, uint4 v) {
    a[0] += bflo(v.x); a[1] += bfhi(v.x); a[2] += bflo(v.y); a[3] += bfhi(v.y);
    a[4] += bflo(v.z); a[5] += bfhi(v.z); a[6] += bflo(v.w); a[7] += bfhi(v.w);
}
__device__ __forceinline__ void set8(float* a, uint4 v) {
    a[0] = bflo(v.x); a[1] = bfhi(v.x); a[2] = bflo(v.y); a[3] = bfhi(v.y);
    a[4] = bflo(v.z); a[5] = bfhi(v.z); a[6] = bflo(v.w); a[7] = bfhi(v.w);
}

// ---------------------------------------------------------------------------
// Fragment-major weights: flat i -> f=i>>9, l=(i>>3)&63, e=i&7; ks=f>>3, c=f&7;
// k = ks*32 + (l>>4)*8 + e; n = c*16 + (l&15).
// MFMA B-read: ((s16x8*)W)[f*64 + lane]  (lane-linear, conflict-free).
// ---------------------------------------------------------------------------
__global__ __launch_bounds__(256) void k_prep1(
    const float* __restrict__ W_h, const float* __restrict__ W_i,
    u16* __restrict__ wt_h, u16* __restrict__ wt_i)
{
    int i = blockIdx.x * 256 + threadIdx.x;
    if (i < Hh * Hh) {                       // wt_h: 32 frags
        int f = i >> 9, l = (i >> 3) & 63, e = i & 7;
        int ks = f >> 3, c = f & 7;
        int k = ks * 32 + (l >> 4) * 8 + e, n = c * 16 + (l & 15);
        wt_h[i] = f2bf(W_h[k * Hh + n]);
    } else {
        int j = i - Hh * Hh;
        if (j < 16 * 512) {                  // wt_i: 16 frags, k<41 else 0
            int f = j >> 9, l = (j >> 3) & 63, e = j & 7;
            int ks = f >> 3, c = f & 7;
            int k = ks * 32 + (l >> 4) * 8 + e, n = c * 16 + (l & 15);
            wt_i[j] = (k < 41) ? f2bf(W_i[k * Hh + n]) : (u16)0;
        }
    }
}

// wt_ot: rows 0..39 of W_o (K padded 64); wt_ob: rows 40..167 of W_o (K=128)
__global__ __launch_bounds__(256) void k_prep_o(
    const float* __restrict__ W_o, u16* __restrict__ wt_ot, u16* __restrict__ wt_ob)
{
    int i = blockIdx.x * 256 + threadIdx.x;
    if (i < 16 * 512) {
        int f = i >> 9, l = (i >> 3) & 63, e = i & 7;
        int ks = f >> 3, c = f & 7;
        int k = ks * 32 + (l >> 4) * 8 + e, n = c * 16 + (l & 15);
        wt_ot[i] = (k < FFn) ? f2bf(W_o[k * Hh + n]) : (u16)0;
    } else {
        int j = i - 16 * 512;
        if (j < 32 * 512) {
            int f = j >> 9, l = (j >> 3) & 63, e = j & 7;
            int ks = f >> 3, c = f & 7;
            int k = ks * 32 + (l >> 4) * 8 + e, n = c * 16 + (l & 15);
            wt_ob[j] = f2bf(W_o[(FFn + k) * Hh + n]);
        }
    }
}

// ---------------------------------------------------------------------------
// k_binput (MFMA, 512 thr): binput_bf = bf16(fedges @ W_i); msg1 = bf16(sigmoid)
// ---------------------------------------------------------------------------
union BinSmem {
    struct { u16 Wi[16 * 512]; u16 A[Hh * KI]; } s;  // 16384 + 18432 B
    float acc[Hh][ACCW];                             // 67584 B
};

__global__ __launch_bounds__(512, 4) void k_binput(
    const float* __restrict__ fedges, const u16* __restrict__ wt_i,
    u16* __restrict__ binput_bf, u16* __restrict__ msg)
{
    __shared__ BinSmem u;
    const int t = threadIdx.x;
    const int row0 = blockIdx.x * 128;
    const int nvalid = min(128, Ee - row0);

    {
        uint4 z = make_uint4(0, 0, 0, 0);
        for (int i = t; i < Hh * KI / 8; i += 512) {
            if (i < 1024) ((uint4*)u.s.Wi)[i] = ((const uint4*)wt_i)[i];
            ((uint4*)u.s.A)[i] = z;
        }
    }
    __syncthreads();
    for (int i = t; i < nvalid * 41; i += 512) {
        int r = i / 41, k = i - r * 41;
        u.s.A[r * KI + k] = f2bf(fedges[(size_t)row0 * 41 + i]);
    }
    __syncthreads();

    const int lane = t & 63, wid = t >> 6, l15 = lane & 15, l4 = lane >> 4;
    f32x4 acc[8];
    #pragma unroll
    for (int b = 0; b < 8; ++b) acc[b] = (f32x4){0.f, 0.f, 0.f, 0.f};

    #pragma unroll
    for (int ks = 0; ks < 2; ++ks) {
        s16x8 a = *(const s16x8*)&u.s.A[(wid * 16 + l15) * KI + ks * 32 + l4 * 8];
        #pragma unroll
        for (int c = 0; c < 8; ++c) {
            s16x8 b = ((const s16x8*)u.s.Wi)[(ks * 8 + c) * 64 + lane];
            acc[c] = __builtin_amdgcn_mfma_f32_16x16x32_bf16(a, b, acc[c], 0, 0, 0);
        }
    }
    __syncthreads();

    #pragma unroll
    for (int c = 0; c < 8; ++c)
        #pragma unroll
        for (int j = 0; j < 4; ++j)
            u.acc[wid * 16 + l4 * 4 + j][c * 16 + l15] = acc[c][j];
    __syncthreads();

    for (int i = t; i < Hh * 16; i += 512) {
        int row = i >> 4, seg = i & 15, grow = row0 + row;
        if (grow < Ee) {
            float4 a0 = *(const float4*)&u.acc[row][seg * 8];
            float4 a1 = *(const float4*)&u.acc[row][seg * 8 + 4];
            size_t o = (size_t)grow * Hh + seg * 8;
            uint4 bv;
            bv.x = pack2(a0.x, a0.y); bv.y = pack2(a0.z, a0.w);
            bv.z = pack2(a1.x, a1.y); bv.w = pack2(a1.z, a1.w);
            *(uint4*)&binput_bf[o] = bv;
            uint4 m;
            m.x = pack2(sigmoidf_(a0.x), sigmoidf_(a0.y));
            m.y = pack2(sigmoidf_(a0.z), sigmoidf_(a0.w));
            m.z = pack2(sigmoidf_(a1.x), sigmoidf_(a1.y));
            m.w = pack2(sigmoidf_(a1.z), sigmoidf_(a1.w));
            *(uint4*)&msg[o] = m;
        }
    }
}

// ---------------------------------------------------------------------------
// k_mmul (MFMA, 256 thr): dst = bf16(src @ Wfrag), K=128.  (used once for T1)
// ---------------------------------------------------------------------------
__global__ __launch_bounds__(256, 4) void k_mmul(
    const u16* __restrict__ src, const u16* __restrict__ wfrag,
    u16* __restrict__ dst, int nrows)
{
    __shared__ union { u16 W[Hh * Hh]; float acc[64][ACC2]; } u;
    const int t = threadIdx.x;
    const int row0 = blockIdx.x * 64;
    const int lane = t & 63, wid = t >> 6, l15 = lane & 15, l4 = lane >> 4;

    for (int i = t; i < Hh * Hh / 8; i += 256)
        ((uint4*)u.W)[i] = ((const uint4*)wfrag)[i];

    const int arow = row0 + wid * 16 + l15;
    s16x8 afrag[4];
    if (arow < nrows) {
        #pragma unroll
        for (int ks = 0; ks < 4; ++ks)
            afrag[ks] = *(const s16x8*)(src + (size_t)arow * Hh + ks * 32 + l4 * 8);
    } else {
        #pragma unroll
        for (int ks = 0; ks < 4; ++ks)
            afrag[ks] = (s16x8){0, 0, 0, 0, 0, 0, 0, 0};
    }
    __syncthreads();

    f32x4 acc[8];
    #pragma unroll
    for (int b = 0; b < 8; ++b) acc[b] = (f32x4){0.f, 0.f, 0.f, 0.f};
    #pragma unroll
    for (int ks = 0; ks < 4; ++ks)
        #pragma unroll
        for (int c = 0; c < 8; ++c) {
            s16x8 b = ((const s16x8*)u.W)[(ks * 8 + c) * 64 + lane];
            acc[c] = __builtin_amdgcn_mfma_f32_16x16x32_bf16(afrag[ks], b, acc[c], 0, 0, 0);
        }
    __syncthreads();

    #pragma unroll
    for (int c = 0; c < 8; ++c)
        #pragma unroll
        for (int j = 0; j < 4; ++j)
            u.acc[wid * 16 + l4 * 4 + j][c * 16 + l15] = acc[c][j];
    __syncthreads();

    for (int i = t; i < 64 * 16; i += 256) {
        int r = i >> 4, seg = i & 15, g = row0 + r;
        if (g < nrows) {
            float4 a0 = *(const float4*)&u.acc[r][seg * 8];
            float4 a1 = *(const float4*)&u.acc[r][seg * 8 + 4];
            uint4 m;
            m.x = pack2(a0.x, a0.y); m.y = pack2(a0.z, a0.w);
            m.z = pack2(a1.x, a1.y); m.w = pack2(a1.z, a1.w);
            *(uint4*)&dst[(size_t)g * Hh + seg * 8] = m;
        }
    }
}

// ---------------------------------------------------------------------------
// k_fused (512 thr, 128 rows): Tout = bf16( sigmoid(binput + sum_8 Tin[eg]) @ W )
// Gather: 8 lanes/row; lane s reads dims [s*8..+8] and [64+s*8..+8] so each
// instruction's 8 lanes cover one full 128B line (1 transaction).  sigmoid'd
// bf16 values are written straight into fragment-major LDS (conflict-balanced),
// then MFMA with LDS frag-major W, acc staged to LDS in two 64-row halves.
// LDS: W 32K + N 32K (union acc 33.3K) + eg 4K = 69.6 KB -> 2 blocks/CU.
// ---------------------------------------------------------------------------
union FusedSmem {
    struct { u16 W[Hh * Hh]; u16 N[Hh * Hh]; } s;   // 32768 + 32768 B
    float acc[64][ACC2];                            // 33280 B
};

__global__ __launch_bounds__(512, 4) void k_fused(
    const u16* __restrict__ Tin, const int* __restrict__ egraph,
    const u16* __restrict__ binput_bf, const u16* __restrict__ wfrag,
    u16* __restrict__ Tout, int nrows)
{
    __shared__ FusedSmem u;
    __shared__ int sEG[128 * NBn];   // 4096 B
    const int t = threadIdx.x;
    const int row0 = blockIdx.x * 128;
    const int lane = t & 63, wid = t >> 6, l15 = lane & 15, l4 = lane >> 4;

    for (int i = t; i < Hh * Hh / 8; i += 512)
        ((uint4*)u.s.W)[i] = ((const uint4*)wfrag)[i];
    if (t < 256) {
        int r = row0 + (t >> 1);
        int4 v = make_int4(0, 0, 0, 0);
        if (r < nrows) v = ((const int4*)egraph)[r * 2 + (t & 1)];
        ((int4*)sEG)[t] = v;
    }
    __syncthreads();

    // gather + sigmoid -> frag-major LDS.  2 passes of 64 rows.
    {
        const int s = t & 7, rl = t >> 3;   // s: dim-slice, rl: 0..63
        #pragma unroll
        for (int p = 0; p < 2; ++p) {
            int r = p * 64 + rl;            // local row 0..127
            int grow = row0 + r;
            float a[16];
            #pragma unroll
            for (int i = 0; i < 16; ++i) a[i] = 0.f;
            if (grow < nrows) {
                {
                    const u16* bb = binput_bf + (size_t)grow * Hh + s * 8;
                    uint4 b0 = *(const uint4*)bb;
                    uint4 b1 = *(const uint4*)(bb + 64);
                    set8(a, b0); set8(a + 8, b1);
                }
                const int* eg = &sEG[r * NBn];
                const u16* base = Tin + (size_t)s * 8;
                const u16* p0 = base + (size_t)eg[0] * Hh;
                const u16* p1 = base + (size_t)eg[1] * Hh;
                const u16* p2 = base + (size_t)eg[2] * Hh;
                const u16* p3 = base + (size_t)eg[3] * Hh;
                const u16* p4 = base + (size_t)eg[4] * Hh;
                const u16* p5 = base + (size_t)eg[5] * Hh;
                const u16* p6 = base + (size_t)eg[6] * Hh;
                const u16* p7 = base + (size_t)eg[7] * Hh;
                uint4 v0a = *(const uint4*)p0, v0b = *(const uint4*)(p0 + 64);
                uint4 v1a = *(const uint4*)p1, v1b = *(const uint4*)(p1 + 64);
                uint4 v2a = *(const uint4*)p2, v2b = *(const uint4*)(p2 + 64);
                uint4 v3a = *(const uint4*)p3, v3b = *(const uint4*)(p3 + 64);
                uint4 v4a = *(const uint4*)p4, v4b = *(const uint4*)(p4 + 64);
                uint4 v5a = *(const uint4*)p5, v5b = *(const uint4*)(p5 + 64);
                uint4 v6a = *(const uint4*)p6, v6b = *(const uint4*)(p6 + 64);
                uint4 v7a = *(const uint4*)p7, v7b = *(const uint4*)(p7 + 64);
                add8(a, v0a); add8(a + 8, v0b);
                add8(a, v1a); add8(a + 8, v1b);
                add8(a, v2a); add8(a + 8, v2b);
                add8(a, v3a); add8(a + 8, v3b);
                add8(a, v4a); add8(a + 8, v4b);
                add8(a, v5a); add8(a + 8, v5b);
                add8(a, v6a); add8(a + 8, v6b);
                add8(a, v7a); add8(a + 8, v7b);
            }
            uint4 o0, o1;
            o0.x = pack2(sigmoidf_(a[0]),  sigmoidf_(a[1]));
            o0.y = pack2(sigmoidf_(a[2]),  sigmoidf_(a[3]));
            o0.z = pack2(sigmoidf_(a[4]),  sigmoidf_(a[5]));
            o0.w = pack2(sigmoidf_(a[6]),  sigmoidf_(a[7]));
            o1.x = pack2(sigmoidf_(a[8]),  sigmoidf_(a[9]));
            o1.y = pack2(sigmoidf_(a[10]), sigmoidf_(a[11]));
            o1.z = pack2(sigmoidf_(a[12]), sigmoidf_(a[13]));
            o1.w = pack2(sigmoidf_(a[14]), sigmoidf_(a[15]));
            // dims s*8   -> frag (ks=s>>2,     l4=s&3); dims 64+s*8 -> ks+2
            int g = r >> 4, rr = r & 15;
            int ksA = s >> 2, l4w = s & 3;
            ((uint4*)u.s.N)[(g * 4 + ksA) * 64 + l4w * 16 + rr]       = o0;
            ((uint4*)u.s.N)[(g * 4 + ksA + 2) * 64 + l4w * 16 + rr]   = o1;
        }
    }
    __syncthreads();

    // MFMA: A-frags lane-linear from sN, B-frags lane-linear from sW
    f32x4 acc[8];
    #pragma unroll
    for (int b = 0; b < 8; ++b) acc[b] = (f32x4){0.f, 0.f, 0.f, 0.f};
    #pragma unroll
    for (int ks = 0; ks < 4; ++ks) {
        s16x8 a = ((const s16x8*)u.s.N)[(wid * 4 + ks) * 64 + lane];
        #pragma unroll
        for (int c = 0; c < 8; ++c) {
            s16x8 b = ((const s16x8*)u.s.W)[(ks * 8 + c) * 64 + lane];
            acc[c] = __builtin_amdgcn_mfma_f32_16x16x32_bf16(a, b, acc[c], 0, 0, 0);
        }
    }
    __syncthreads();   // all LDS reads done -> union region reusable

    // epilogue: two 64-row halves through the union acc buffer
    #pragma unroll
    for (int h = 0; h < 2; ++h) {
        if ((wid >> 2) == h) {
            #pragma unroll
            for (int c = 0; c < 8; ++c)
                #pragma unroll
                for (int j = 0; j < 4; ++j)
                    u.acc[(wid & 3) * 16 + l4 * 4 + j][c * 16 + l15] = acc[c][j];
        }
        __syncthreads();
        for (int i = t; i < 64 * 16; i += 512) {
            int r = i >> 4, seg = i & 15;
            int g = row0 + h * 64 + r;
            if (g < nrows) {
                float4 a0 = *(const float4*)&u.acc[r][seg * 8];
                float4 a1 = *(const float4*)&u.acc[r][seg * 8 + 4];
                uint4 m;
                m.x = pack2(a0.x, a0.y); m.y = pack2(a0.z, a0.w);
                m.z = pack2(a1.x, a1.y); m.w = pack2(a1.z, a1.w);
                *(uint4*)&Tout[(size_t)g * Hh + seg * 8] = m;
            }
        }
        __syncthreads();
    }
}

// ---------------------------------------------------------------------------
// k_gscatter_sig: out[row] = bf16(sigmoid(base[row] + sum_8 T[graph[row][j]]))
// 8 lanes/row; lane s covers dims [s*8] and [64+s*8] -> 128B-contiguous
// per instruction.  No LDS, no barriers.
// ---------------------------------------------------------------------------
__global__ __launch_bounds__(256, 4) void k_gscatter_sig(
    const u16* __restrict__ T, const int* __restrict__ graph,
    const u16* __restrict__ base, u16* __restrict__ out, int nrows)
{
    const int gid = blockIdx.x * 256 + threadIdx.x;
    const int row = gid >> 3;
    const int s   = gid & 7;
    if (row >= nrows) return;

    const int4 q0 = ((const int4*)graph)[row * 2];
    const int4 q1 = ((const int4*)graph)[row * 2 + 1];
    const u16* bp = T + (size_t)s * 8;

    const u16* p0 = bp + (size_t)q0.x * Hh;
    const u16* p1 = bp + (size_t)q0.y * Hh;
    const u16* p2 = bp + (size_t)q0.z * Hh;
    const u16* p3 = bp + (size_t)q0.w * Hh;
    const u16* p4 = bp + (size_t)q1.x * Hh;
    const u16* p5 = bp + (size_t)q1.y * Hh;
    const u16* p6 = bp + (size_t)q1.z * Hh;
    const u16* p7 = bp + (size_t)q1.w * Hh;

    uint4 v0a = *(const uint4*)p0, v0b = *(const uint4*)(p0 + 64);
    uint4 v1a = *(const uint4*)p1, v1b = *(const uint4*)(p1 + 64);
    uint4 v2a = *(const uint4*)p2, v2b = *(const uint4*)(p2 + 64);
    uint4 v3a = *(const uint4*)p3, v3b = *(const uint4*)(p3 + 64);
    uint4 v4a = *(const uint4*)p4, v4b = *(const uint4*)(p4 + 64);
    uint4 v5a = *(const uint4*)p5, v5b = *(const uint4*)(p5 + 64);
    uint4 v6a = *(const uint4*)p6, v6b = *(const uint4*)(p6 + 64);
    uint4 v7a = *(const uint4*)p7, v7b = *(const uint4*)(p7 + 64);

    const u16* bs = base + (size_t)row * Hh + (size_t)s * 8;
    uint4 b0 = *(const uint4*)bs, b1 = *(const uint4*)(bs + 64);

    float a[16];
    set8(a, b0); set8(a + 8, b1);
    add8(a, v0a); add8(a + 8, v0b);
    add8(a, v1a); add8(a + 8, v1b);
    add8(a, v2a); add8(a + 8, v2b);
    add8(a, v3a); add8(a + 8, v3b);
    add8(a, v4a); add8(a + 8, v4b);
    add8(a, v5a); add8(a + 8, v5b);
    add8(a, v6a); add8(a + 8, v6b);
    add8(a, v7a); add8(a + 8, v7b);

    uint4 o0, o1;
    o0.x = pack2(sigmoidf_(a[0]),  sigmoidf_(a[1]));
    o0.y = pack2(sigmoidf_(a[2]),  sigmoidf_(a[3]));
    o0.z = pack2(sigmoidf_(a[4]),  sigmoidf_(a[5]));
    o0.w = pack2(sigmoidf_(a[6]),  sigmoidf_(a[7]));
    o1.x = pack2(sigmoidf_(a[8]),  sigmoidf_(a[9]));
    o1.y = pack2(sigmoidf_(a[10]), sigmoidf_(a[11]));
    o1.z = pack2(sigmoidf_(a[12]), sigmoidf_(a[13]));
    o1.w = pack2(sigmoidf_(a[14]), sigmoidf_(a[15]));
    u16* q = out + (size_t)row * Hh + (size_t)s * 8;
    *(uint4*)q        = o0;
    *(uint4*)(q + 64) = o1;
}

// ---------------------------------------------------------------------------
// k_fgemm (MFMA, 256 thr): F = bf16(features @ Wo_top + b_o), K=64 (padded 40)
// ---------------------------------------------------------------------------
union FSmem {
    struct { u16 Wi[16 * 512]; u16 A[64 * KI]; } s;  // 16384 + 9216 B
    float acc[64][ACCW];                             // 33792 B
};

__global__ __launch_bounds__(256, 4) void k_fgemm(
    const float* __restrict__ features, const u16* __restrict__ wt_ot,
    const float* __restrict__ b_o, u16* __restrict__ F)
{
    __shared__ FSmem u;
    __shared__ float sBias[Hh];
    const int t = threadIdx.x;
    const int row0 = blockIdx.x * 64;
    const int nvalid = min(64, Nn - row0);

    for (int i = t; i < 16 * 512 / 8; i += 256)
        ((uint4*)u.s.Wi)[i] = ((const uint4*)wt_ot)[i];
    {
        uint4 z = make_uint4(0, 0, 0, 0);
        for (int i = t; i < 64 * KI / 8; i += 256) ((uint4*)u.s.A)[i] = z;
    }
    if (t < Hh / 4) ((float4*)sBias)[t] = ((const float4*)b_o)[t];
    __syncthreads();
    for (int i = t; i < nvalid * FFn; i += 256) {
        int r = i / FFn, k = i - r * FFn;
        u.s.A[r * KI + k] = f2bf(features[(size_t)row0 * FFn + i]);
    }
    __syncthreads();

    const int lane = t & 63, wid = t >> 6, l15 = lane & 15, l4 = lane >> 4;
    f32x4 acc[8];
    #pragma unroll
    for (int b = 0; b < 8; ++b) acc[b] = (f32x4){0.f, 0.f, 0.f, 0.f};
    #pragma unroll
    for (int ks = 0; ks < 2; ++ks) {
        s16x8 a = *(const s16x8*)&u.s.A[(wid * 16 + l15) * KI + ks * 32 + l4 * 8];
        #pragma unroll
        for (int c = 0; c < 8; ++c) {
            s16x8 b = ((const s16x8*)u.s.Wi)[(ks * 8 + c) * 64 + lane];
            acc[c] = __builtin_amdgcn_mfma_f32_16x16x32_bf16(a, b, acc[c], 0, 0, 0);
        }
    }
    __syncthreads();

    #pragma unroll
    for (int c = 0; c < 8; ++c)
        #pragma unroll
        for (int j = 0; j < 4; ++j)
            u.acc[wid * 16 + l4 * 4 + j][c * 16 + l15] = acc[c][j];
    __syncthreads();

    for (int i = t; i < 64 * 16; i += 256) {
        int r = i >> 4, seg = i & 15, g = row0 + r;
        if (g < Nn) {
            float4 a0 = *(const float4*)&u.acc[r][seg * 8];
            float4 a1 = *(const float4*)&u.acc[r][seg * 8 + 4];
            const float* bb = &sBias[seg * 8];
            uint4 m;
            m.x = pack2(a0.x + bb[0], a0.y + bb[1]);
            m.y = pack2(a0.z + bb[2], a0.w + bb[3]);
            m.z = pack2(a1.x + bb[4], a1.y + bb[5]);
            m.w = pack2(a1.z + bb[6], a1.w + bb[7]);
            *(uint4*)&F[(size_t)g * Hh + seg * 8] = m;
        }
    }
}

// ---------------------------------------------------------------------------
// k_pool: segment mean over bf16 hidden. One block (128 threads) / molecule.
// ---------------------------------------------------------------------------
__global__ __launch_bounds__(128) void k_pool(
    const u16* __restrict__ hidden, const int* __restrict__ scope,
    float* __restrict__ out)
{
    const int b = blockIdx.x;
    const int t = threadIdx.x;
    const int start = scope[b * 2 + 0];
    const int len   = scope[b * 2 + 1];
    float acc = 0.f;
    for (int i = 0; i < len; ++i)
        acc += bf1(hidden[(size_t)(start + i) * Hh + t]);
    out[(size_t)b * Hh + t] = acc / (float)len;
}

// ---------------------------------------------------------------------------
extern "C" void kernel_launch(void* const* d_in, const int* in_sizes, int n_in,
                              void* d_out, int out_size, void* d_ws, size_t ws_size,
                              hipStream_t stream)
{
    const float* features = (const float*)d_in[0];
    const float* fedges   = (const float*)d_in[1];
    const int*   agraph   = (const int*)d_in[2];
    const int*   egraph   = (const int*)d_in[3];
    const int*   scope    = (const int*)d_in[4];
    const float* W_i      = (const float*)d_in[5];
    const float* W_h      = (const float*)d_in[6];
    const float* W_o      = (const float*)d_in[7];
    const float* b_o      = (const float*)d_in[8];
    float* out = (float*)d_out;

    // Workspace planes (u16, E*128 each): binput | P1 | Ta | Tb | wt_h tail.
    // P1 holds msg1 (consumed by the T1 k_mmul), then wt_ot/wt_ob/F/hidden.
    // wt_i parks in Ta (consumed by k_binput before k_mmul writes Ta).
    const size_t plane = (size_t)Ee * Hh;
    u16* binput = (u16*)d_ws;
    u16* P1     = binput + plane;
    u16* Ta     = P1 + plane;
    u16* Tb     = Ta + plane;
    u16* wt_h   = Tb + plane;                // 16384 u16
    u16* msg1   = P1;
    u16* wt_i   = Ta;                        // 8192 u16
    u16* wt_ot  = P1;                        // 8192 u16
    u16* wt_ob  = P1 + 16 * 512;             // 16384 u16
    u16* Fbuf   = P1 + 16 * 512 + 32 * 512;          // Nn*128 u16
    u16* hidden = Fbuf + (size_t)Nn * Hh;            // Nn*128 u16

    k_prep1<<<(Hh * Hh + 16 * 512 + 255) / 256, 256, 0, stream>>>(W_h, W_i, wt_h, wt_i);

    k_binput<<<(Ee + 127) / 128, 512, 0, stream>>>(fedges, wt_i, binput, msg1);

    // T1 = msg1 @ W_h   (msg1/P1 dead afterwards)
    k_mmul<<<(Ee + 63) / 64, 256, 0, stream>>>(msg1, wt_h, Ta, Ee);
    k_prep_o<<<(48 * 512) / 256, 256, 0, stream>>>(W_o, wt_ot, wt_ob);
    k_fgemm<<<(Nn + 63) / 64, 256, 0, stream>>>(features, wt_ot, b_o, Fbuf);

    const int fblocks = (Ee + 127) / 128;
    u16* src = Ta;
    u16* dst = Tb;
    for (int d = 0; d < 4; ++d) {           // T2..T5 (with W_h)
        k_fused<<<fblocks, 512, 0, stream>>>(src, egraph, binput, wt_h, dst, Ee);
        u16* tmp = src; src = dst; dst = tmp;
    }
    // last update: msg6 internally, output U = msg6 @ Wo_bot
    k_fused<<<fblocks, 512, 0, stream>>>(src, egraph, binput, wt_ob, dst, Ee);
    u16* U = dst;

    k_gscatter_sig<<<(Nn * NBn + 255) / 256, 256, 0, stream>>>(U, agraph, Fbuf, hidden, Nn);

    k_pool<<<Bm, 128, 0, stream>>>(hidden, scope, out);
}

// Round 9
// 425.492 us; speedup vs baseline: 1.7320x; 1.7320x over previous
//
#include <hip/hip_runtime.h>

// PhaMPN v9: v4 structure + weights-from-global (L1/L2) + higher occupancy.
//   binput = fedges @ W_i (MFMA, bf16); msg = bf16(sigmoid(binput))
//   5x: msg = bf16(sigmoid(binput + (sum_8 msg[egraph]) @ W_h))   [k_iter]
//   hidden = bf16(sigmoid([feat|nei] @ W_o + b_o))                [k_final]
//   out = segment-mean(hidden) per scope row (B=500, len=100), f32
// v9: k_iter/k_final read B-fragments directly from global frag-major weight
//     tables (L1/L2-resident) instead of staging to LDS -> LDS 38.9/36.3 KB ->
//     3-4 blocks/CU (was 2).  Gather shapes and rounding identical to v4.

typedef __attribute__((ext_vector_type(4))) float f32x4;
typedef __attribute__((ext_vector_type(8))) short s16x8;
typedef unsigned short u16;

constexpr int Nn   = 50000;
constexpr int Ee   = 150000;
constexpr int NBn  = 8;
constexpr int Hh   = 128;
constexpr int FFn  = 40;
constexpr int Bm   = 500;
constexpr int ITERS = 5;       // DEPTH - 1
constexpr int KP   = 136;      // nei-tile bf16 row stride (k_iter)
constexpr int KI   = 72;       // fedges-tile stride (K padded 41->64)
constexpr int KO   = 200;      // k_final A-tile stride (K padded 168->192)
constexpr int ACCW = 132;      // f32 acc stride (k_binput / k_final)
constexpr int ACC2 = 130;      // f32 acc stride (k_iter halves)

__device__ __forceinline__ float sigmoidf_(float x) {
    return 1.0f / (1.0f + __expf(-x));
}
// f32 -> bf16 round-to-nearest-even (finite values only)
__device__ __forceinline__ u16 f2bf(float f) {
    unsigned u = __float_as_uint(f);
    u += 0x7fffu + ((u >> 16) & 1u);
    return (u16)(u >> 16);
}
__device__ __forceinline__ float bflo(unsigned u) { return __uint_as_float(u << 16); }
__device__ __forceinline__ float bfhi(unsigned u) { return __uint_as_float(u & 0xffff0000u); }
__device__ __forceinline__ float bf1(u16 h) { return __uint_as_float(((unsigned)h) << 16); }
__device__ __forceinline__ unsigned pack2(float x, float y) {
    return (unsigned)f2bf(x) | ((unsigned)f2bf(y) << 16);
}
__device__ __forceinline__ void add8(float* a, uint4 v) {
    a[0] += bflo(v.x); a[1] += bfhi(v.x); a[2] += bflo(v.y); a[3] += bfhi(v.y);
    a[4] += bflo(v.z); a[5] += bfhi(v.z); a[6] += bflo(v.w); a[7] += bfhi(v.w);
}

// ---------------------------------------------------------------------------
// Fragment-major weights: flat i -> f=i>>9, l=(i>>3)&63, e=i&7; ks=f>>3, c=f&7;
// k = ks*32 + (l>>4)*8 + e; n = c*16 + (l&15).
// MFMA B-read: ((s16x8*)W)[f*64 + lane]  (lane-linear 1KB/instr, cacheable).
// ---------------------------------------------------------------------------
__global__ __launch_bounds__(256) void k_prep1(
    const float* __restrict__ W_h, const float* __restrict__ W_i,
    u16* __restrict__ wt_h, u16* __restrict__ wt_i)
{
    int i = blockIdx.x * 256 + threadIdx.x;
    if (i < Hh * Hh) {                       // wt_h: 32 frags
        int f = i >> 9, l = (i >> 3) & 63, e = i & 7;
        int ks = f >> 3, c = f & 7;
        int k = ks * 32 + (l >> 4) * 8 + e, n = c * 16 + (l & 15);
        wt_h[i] = f2bf(W_h[k * Hh + n]);
    } else {
        int j = i - Hh * Hh;
        if (j < 16 * 512) {                  // wt_i: 16 frags, k<41 else 0
            int f = j >> 9, l = (j >> 3) & 63, e = j & 7;
            int ks = f >> 3, c = f & 7;
            int k = ks * 32 + (l >> 4) * 8 + e, n = c * 16 + (l & 15);
            wt_i[j] = (k < 41) ? f2bf(W_i[k * Hh + n]) : (u16)0;
        }
    }
}

// wt_o: 48 frags; k<40 -> W_o[k][n]; 40..63 -> 0; 64..191 -> W_o[k-24][n]
__global__ __launch_bounds__(256) void k_prep2(
    const float* __restrict__ W_o, u16* __restrict__ wt_o)
{
    int i = blockIdx.x * 256 + threadIdx.x;
    if (i < 48 * 512) {
        int f = i >> 9, l = (i >> 3) & 63, e = i & 7;
        int ks = f >> 3, c = f & 7;
        int k = ks * 32 + (l >> 4) * 8 + e, n = c * 16 + (l & 15);
        u16 v = 0;
        if (k < FFn)                 v = f2bf(W_o[k * Hh + n]);
        else if (k >= 64 && k < 192) v = f2bf(W_o[(k - 24) * Hh + n]);
        wt_o[i] = v;
    }
}

// ---------------------------------------------------------------------------
// k_binput (MFMA, 512 thr): binput_bf = bf16(fedges @ W_i); msg = bf16(sigmoid)
// 128 rows / block, 8 waves, K=64 (padded).  (unchanged from v4-lineage)
// ---------------------------------------------------------------------------
union BinSmem {
    struct { u16 Wi[16 * 512]; u16 A[Hh * KI]; } s;  // 16384 + 18432 B
    float acc[Hh][ACCW];                             // 67584 B
};

__global__ __launch_bounds__(512, 4) void k_binput(
    const float* __restrict__ fedges, const u16* __restrict__ wt_i,
    u16* __restrict__ binput_bf, u16* __restrict__ msg)
{
    __shared__ BinSmem u;
    const int t = threadIdx.x;
    const int row0 = blockIdx.x * 128;
    const int nvalid = min(128, Ee - row0);

    {
        uint4 z = make_uint4(0, 0, 0, 0);
        for (int i = t; i < Hh * KI / 8; i += 512) {
            if (i < 1024) ((uint4*)u.s.Wi)[i] = ((const uint4*)wt_i)[i];
            ((uint4*)u.s.A)[i] = z;
        }
    }
    __syncthreads();
    for (int i = t; i < nvalid * 41; i += 512) {
        int r = i / 41, k = i - r * 41;
        u.s.A[r * KI + k] = f2bf(fedges[(size_t)row0 * 41 + i]);
    }
    __syncthreads();

    const int lane = t & 63, wid = t >> 6, l15 = lane & 15, l4 = lane >> 4;
    f32x4 acc[8];
    #pragma unroll
    for (int b = 0; b < 8; ++b) acc[b] = (f32x4){0.f, 0.f, 0.f, 0.f};

    #pragma unroll
    for (int ks = 0; ks < 2; ++ks) {
        s16x8 a = *(const s16x8*)&u.s.A[(wid * 16 + l15) * KI + ks * 32 + l4 * 8];
        #pragma unroll
        for (int c = 0; c < 8; ++c) {
            s16x8 b = ((const s16x8*)u.s.Wi)[(ks * 8 + c) * 64 + lane];
            acc[c] = __builtin_amdgcn_mfma_f32_16x16x32_bf16(a, b, acc[c], 0, 0, 0);
        }
    }
    __syncthreads();

    #pragma unroll
    for (int c = 0; c < 8; ++c)
        #pragma unroll
        for (int j = 0; j < 4; ++j)
            u.acc[wid * 16 + l4 * 4 + j][c * 16 + l15] = acc[c][j];
    __syncthreads();

    for (int i = t; i < Hh * 16; i += 512) {
        int row = i >> 4, seg = i & 15, grow = row0 + row;
        if (grow < Ee) {
            float4 a0 = *(const float4*)&u.acc[row][seg * 8];
            float4 a1 = *(const float4*)&u.acc[row][seg * 8 + 4];
            size_t o = (size_t)grow * Hh + seg * 8;
            uint4 bv;
            bv.x = pack2(a0.x, a0.y); bv.y = pack2(a0.z, a0.w);
            bv.z = pack2(a1.x, a1.y); bv.w = pack2(a1.z, a1.w);
            *(uint4*)&binput_bf[o] = bv;
            uint4 m;
            m.x = pack2(sigmoidf_(a0.x), sigmoidf_(a0.y));
            m.y = pack2(sigmoidf_(a0.z), sigmoidf_(a0.w));
            m.z = pack2(sigmoidf_(a1.x), sigmoidf_(a1.y));
            m.w = pack2(sigmoidf_(a1.z), sigmoidf_(a1.w));
            *(uint4*)&msg[o] = m;
        }
    }
}

// ---------------------------------------------------------------------------
// k_iter (MFMA, 512 thr, 128 rows): msg_out = bf16(sigmoid(binput + nei@W_h))
// v4 gather (16 lanes/row x 16B -> full 256B row per instruction) into
// [row][KP] LDS; MFMA A from LDS, B from GLOBAL frag-major wt_h (L1-resident);
// two-64-row-half f32 epilogue through the union.
// LDS: union(N 34.8KB | acc 33.3KB) + sEG 4KB = 38.9 KB -> 3 blocks/CU.
// ---------------------------------------------------------------------------
union IterSmem {
    u16 N[Hh * KP];             // 34816 B
    float acc[64][ACC2];        // 33280 B
};

__global__ __launch_bounds__(512, 6) void k_iter(
    const u16* __restrict__ msg_in, const int* __restrict__ egraph,
    const u16* __restrict__ wt_h, const u16* __restrict__ binput_bf,
    u16* __restrict__ msg_out)
{
    __shared__ IterSmem u;
    __shared__ int sEG[128 * NBn];
    const int t = threadIdx.x;
    const int row0 = blockIdx.x * 128;
    const int lane = t & 63, wid = t >> 6, l15 = lane & 15, l4 = lane >> 4;

    if (t < 256) {
        int r = row0 + (t >> 1);
        int4 v = make_int4(0, 0, 0, 0);
        if (r < Ee) v = ((const int4*)egraph)[r * 2 + (t & 1)];
        ((int4*)sEG)[t] = v;
    }
    __syncthreads();

    // gather: 16 lanes/row x 16B; 32 rows per pass, 4 passes  (v4-identical)
    {
        const int s = t & 15, rl = t >> 4;
        #pragma unroll 2
        for (int pass = 0; pass < 4; ++pass) {
            int r = pass * 32 + rl;
            int grow = row0 + r;
            float a[8] = {0.f, 0.f, 0.f, 0.f, 0.f, 0.f, 0.f, 0.f};
            if (grow < Ee) {
                #pragma unroll
                for (int j = 0; j < NBn; ++j) {
                    int idx = sEG[r * NBn + j];
                    uint4 v = *(const uint4*)(msg_in + (size_t)idx * Hh + s * 8);
                    add8(a, v);
                }
            }
            uint4 o;
            o.x = pack2(a[0], a[1]); o.y = pack2(a[2], a[3]);
            o.z = pack2(a[4], a[5]); o.w = pack2(a[6], a[7]);
            *(uint4*)&u.N[r * KP + s * 8] = o;
        }
    }
    __syncthreads();

    // MFMA: A from LDS (v4 pattern), B from global frag-major table
    f32x4 acc[8];
    #pragma unroll
    for (int b = 0; b < 8; ++b) acc[b] = (f32x4){0.f, 0.f, 0.f, 0.f};
    #pragma unroll
    for (int ks = 0; ks < 4; ++ks) {
        s16x8 a = *(const s16x8*)&u.N[(wid * 16 + l15) * KP + ks * 32 + l4 * 8];
        #pragma unroll
        for (int c = 0; c < 8; ++c) {
            s16x8 b = ((const s16x8*)wt_h)[(ks * 8 + c) * 64 + lane];
            acc[c] = __builtin_amdgcn_mfma_f32_16x16x32_bf16(a, b, acc[c], 0, 0, 0);
        }
    }
    __syncthreads();   // all LDS A-reads done -> union region reusable

    // epilogue: two 64-row halves through the union acc buffer (v8-verified)
    #pragma unroll
    for (int h = 0; h < 2; ++h) {
        if ((wid >> 2) == h) {
            #pragma unroll
            for (int c = 0; c < 8; ++c)
                #pragma unroll
                for (int j = 0; j < 4; ++j)
                    u.acc[(wid & 3) * 16 + l4 * 4 + j][c * 16 + l15] = acc[c][j];
        }
        __syncthreads();
        for (int i = t; i < 64 * 16; i += 512) {
            int r = i >> 4, seg = i & 15;
            int g = row0 + h * 64 + r;
            if (g < Ee) {
                float4 a0 = *(const float4*)&u.acc[r][seg * 8];
                float4 a1 = *(const float4*)&u.acc[r][seg * 8 + 4];
                size_t o = (size_t)g * Hh + seg * 8;
                uint4 bv = *(const uint4*)&binput_bf[o];
                uint4 m;
                m.x = pack2(sigmoidf_(a0.x + bflo(bv.x)), sigmoidf_(a0.y + bfhi(bv.x)));
                m.y = pack2(sigmoidf_(a0.z + bflo(bv.y)), sigmoidf_(a0.w + bfhi(bv.y)));
                m.z = pack2(sigmoidf_(a1.x + bflo(bv.z)), sigmoidf_(a1.y + bfhi(bv.z)));
                m.w = pack2(sigmoidf_(a1.z + bflo(bv.w)), sigmoidf_(a1.w + bfhi(bv.w)));
                *(uint4*)&msg_out[o] = m;
            }
        }
        __syncthreads();
    }
}

// ---------------------------------------------------------------------------
// k_final (MFMA, 256 thr, 64 rows): hidden = bf16(sigmoid([feat|0|nei]@W_o+b))
// B from GLOBAL frag-major wt_o (L2-resident); LDS = union(A | acc) 33.8KB
// + ag 2KB + bias 0.5KB = 36.3 KB -> 4 blocks/CU (was 2 at 77KB).
// ---------------------------------------------------------------------------
union FinSmem {
    u16 A[64 * KO];         // 25600 B
    float acc[64][ACCW];    // 33792 B
};

__global__ __launch_bounds__(256, 4) void k_final(
    const u16* __restrict__ msg_in, const int* __restrict__ agraph,
    const float* __restrict__ features, const u16* __restrict__ wt_o,
    const float* __restrict__ b_o, u16* __restrict__ hidden)
{
    __shared__ FinSmem u;
    __shared__ int sAG[64 * NBn];   // 2048 B
    __shared__ float sBias[Hh];     // 512 B
    const int t = threadIdx.x;
    const int row0 = blockIdx.x * 64;
    const int nvalid = min(64, Nn - row0);

    {
        uint4 z = make_uint4(0, 0, 0, 0);
        for (int i = t; i < 64 * KO / 8; i += 256) ((uint4*)u.A)[i] = z;
    }
    if (t < 128) {
        int r = row0 + (t >> 1);
        int4 v = make_int4(0, 0, 0, 0);
        if (r < Nn) v = ((const int4*)agraph)[r * 2 + (t & 1)];
        ((int4*)sAG)[t] = v;
    }
    if (t < Hh / 4) ((float4*)sBias)[t] = ((const float4*)b_o)[t];
    __syncthreads();

    for (int i = t; i < nvalid * FFn; i += 256) {
        int r = i / FFn, k = i - r * FFn;
        u.A[r * KO + k] = f2bf(features[(size_t)row0 * FFn + i]);
    }
    {
        const int s = t & 15, rl = t >> 4;
        #pragma unroll 2
        for (int pass = 0; pass < 4; ++pass) {
            int r = pass * 16 + rl;
            int grow = row0 + r;
            float a[8] = {0.f, 0.f, 0.f, 0.f, 0.f, 0.f, 0.f, 0.f};
            if (grow < Nn) {
                #pragma unroll
                for (int j = 0; j < NBn; ++j) {
                    int idx = sAG[r * NBn + j];
                    uint4 v = *(const uint4*)(msg_in + (size_t)idx * Hh + s * 8);
                    add8(a, v);
                }
            }
            uint4 o;
            o.x = pack2(a[0], a[1]); o.y = pack2(a[2], a[3]);
            o.z = pack2(a[4], a[5]); o.w = pack2(a[6], a[7]);
            *(uint4*)&u.A[r * KO + 64 + s * 8] = o;
        }
    }
    __syncthreads();

    const int lane = t & 63, wid = t >> 6, l15 = lane & 15, l4 = lane >> 4;
    f32x4 acc[8];
    #pragma unroll
    for (int b = 0; b < 8; ++b) acc[b] = (f32x4){0.f, 0.f, 0.f, 0.f};

    #pragma unroll
    for (int ks = 0; ks < 6; ++ks) {
        s16x8 a = *(const s16x8*)&u.A[(wid * 16 + l15) * KO + ks * 32 + l4 * 8];
        #pragma unroll
        for (int c = 0; c < 8; ++c) {
            s16x8 b = ((const s16x8*)wt_o)[(ks * 8 + c) * 64 + lane];
            acc[c] = __builtin_amdgcn_mfma_f32_16x16x32_bf16(a, b, acc[c], 0, 0, 0);
        }
    }
    __syncthreads();   // A reads done -> union reusable

    #pragma unroll
    for (int c = 0; c < 8; ++c)
        #pragma unroll
        for (int j = 0; j < 4; ++j)
            u.acc[wid * 16 + l4 * 4 + j][c * 16 + l15] = acc[c][j];
    __syncthreads();

    for (int i = t; i < 64 * 16; i += 256) {
        int r = i >> 4, seg = i & 15, g = row0 + r;
        if (g < Nn) {
            float4 a0 = *(const float4*)&u.acc[r][seg * 8];
            float4 a1 = *(const float4*)&u.acc[r][seg * 8 + 4];
            const float* bb = &sBias[seg * 8];
            uint4 m;
            m.x = pack2(sigmoidf_(a0.x + bb[0]), sigmoidf_(a0.y + bb[1]));
            m.y = pack2(sigmoidf_(a0.z + bb[2]), sigmoidf_(a0.w + bb[3]));
            m.z = pack2(sigmoidf_(a1.x + bb[4]), sigmoidf_(a1.y + bb[5]));
            m.w = pack2(sigmoidf_(a1.z + bb[6]), sigmoidf_(a1.w + bb[7]));
            *(uint4*)&hidden[(size_t)g * Hh + seg * 8] = m;
        }
    }
}

// ---------------------------------------------------------------------------
// k_pool: segment mean over bf16 hidden. One block (128 threads) / molecule.
// ---------------------------------------------------------------------------
__global__ __launch_bounds__(128) void k_pool(
    const u16* __restrict__ hidden, const int* __restrict__ scope,
    float* __restrict__ out)
{
    const int b = blockIdx.x;
    const int t = threadIdx.x;
    const int start = scope[b * 2 + 0];
    const int len   = scope[b * 2 + 1];
    float acc = 0.f;
    for (int i = 0; i < len; ++i)
        acc += bf1(hidden[(size_t)(start + i) * Hh + t]);
    out[(size_t)b * Hh + t] = acc / (float)len;
}

// ---------------------------------------------------------------------------
extern "C" void kernel_launch(void* const* d_in, const int* in_sizes, int n_in,
                              void* d_out, int out_size, void* d_ws, size_t ws_size,
                              hipStream_t stream)
{
    const float* features = (const float*)d_in[0];
    const float* fedges   = (const float*)d_in[1];
    const int*   agraph   = (const int*)d_in[2];
    const int*   egraph   = (const int*)d_in[3];
    const int*   scope    = (const int*)d_in[4];
    const float* W_i      = (const float*)d_in[5];
    const float* W_h      = (const float*)d_in[6];
    const float* W_o      = (const float*)d_in[7];
    const float* b_o      = (const float*)d_in[8];
    float* out = (float*)d_out;

    // Workspace planes (u16, E*128 each): binput | msg0 | msg1 | wt_h tail.
    // wt_i parks in msg1 (consumed by k_binput before iter0 writes msg1);
    // wt_o (48*512 u16) parks in binput region (dead after the last k_iter).
    const size_t plane = (size_t)Ee * Hh;
    u16* binput_bf = (u16*)d_ws;
    u16* msg0 = binput_bf + plane;
    u16* msg1 = msg0 + plane;
    u16* wt_h = msg1 + plane;       // 16384 u16
    u16* wt_i = msg1;               // 8192 u16
    u16* wt_o = binput_bf;          // 24576 u16

    k_prep1<<<(Hh * Hh + 16 * 512 + 255) / 256, 256, 0, stream>>>(W_h, W_i, wt_h, wt_i);

    const int eblocks = (Ee + 127) / 128;
    k_binput<<<eblocks, 512, 0, stream>>>(fedges, wt_i, binput_bf, msg0);

    u16* src = msg0;
    u16* dst = msg1;
    for (int d = 0; d < ITERS; ++d) {
        k_iter<<<eblocks, 512, 0, stream>>>(src, egraph, wt_h, binput_bf, dst);
        u16* tmp = src; src = dst; dst = tmp;
    }
    // final message in `src` (= msg1); binput now dead -> prep wt_o there.
    k_prep2<<<(48 * 512) / 256, 256, 0, stream>>>(W_o, wt_o);

    u16* hidden = dst;   // = msg0 region (dead)
    const int nblocks = (Nn + 63) / 64;
    k_final<<<nblocks, 256, 0, stream>>>(src, agraph, features, wt_o, b_o, hidden);

    k_pool<<<Bm, 128, 0, stream>>>(hidden, scope, out);
}

// Round 10
// 293.046 us; speedup vs baseline: 2.5148x; 1.4520x over previous
//
#include <hip/hip_runtime.h>

// PhaMPN v10: v9 structure + fp8(e4m3) message storage.
//   binput = fedges @ W_i (MFMA, stored bf16); msg = fp8(sigmoid(binput))
//   5x: msg = fp8(sigmoid(binput + (sum_8 msg[egraph]) @ W_h))   [k_iter]
//   hidden = bf16(sigmoid([feat|nei] @ W_o + b_o))               [k_final]
//   out = segment-mean(hidden), f32
// fp8 msg rows are 128 B (2 sectors, was 4) -> gather request volume halves.
// GEMM stays bf16 (gather sums requantized to bf16 in LDS); binput stays bf16.

typedef __attribute__((ext_vector_type(4))) float f32x4;
typedef __attribute__((ext_vector_type(2))) float f32x2;
typedef __attribute__((ext_vector_type(8))) short s16x8;
typedef unsigned short u16;
typedef unsigned char u8;

constexpr int Nn   = 50000;
constexpr int Ee   = 150000;
constexpr int NBn  = 8;
constexpr int Hh   = 128;
constexpr int FFn  = 40;
constexpr int Bm   = 500;
constexpr int ITERS = 5;       // DEPTH - 1
constexpr int KP   = 136;      // nei-tile bf16 row stride (k_iter)
constexpr int KI   = 72;       // fedges-tile stride (K padded 41->64)
constexpr int KO   = 200;      // k_final A-tile stride (K padded 168->192)
constexpr int ACCW = 132;      // f32 acc stride (k_binput / k_final)
constexpr int ACC2 = 130;      // f32 acc stride (k_iter halves)

__device__ __forceinline__ float sigmoidf_(float x) {
    return 1.0f / (1.0f + __expf(-x));
}
// f32 -> bf16 round-to-nearest-even (finite values only)
__device__ __forceinline__ u16 f2bf(float f) {
    unsigned u = __float_as_uint(f);
    u += 0x7fffu + ((u >> 16) & 1u);
    return (u16)(u >> 16);
}
__device__ __forceinline__ float bflo(unsigned u) { return __uint_as_float(u << 16); }
__device__ __forceinline__ float bfhi(unsigned u) { return __uint_as_float(u & 0xffff0000u); }
__device__ __forceinline__ float bf1(u16 h) { return __uint_as_float(((unsigned)h) << 16); }
__device__ __forceinline__ unsigned pack2(float x, float y) {
    return (unsigned)f2bf(x) | ((unsigned)f2bf(y) << 16);
}
// fp8 e4m3 (OCP on gfx950) HW converts
__device__ __forceinline__ void add8f8(float* a, uint2 v) {
    f32x2 p;
    p = __builtin_amdgcn_cvt_pk_f32_fp8((int)v.x, false); a[0] += p[0]; a[1] += p[1];
    p = __builtin_amdgcn_cvt_pk_f32_fp8((int)v.x, true);  a[2] += p[0]; a[3] += p[1];
    p = __builtin_amdgcn_cvt_pk_f32_fp8((int)v.y, false); a[4] += p[0]; a[5] += p[1];
    p = __builtin_amdgcn_cvt_pk_f32_fp8((int)v.y, true);  a[6] += p[0]; a[7] += p[1];
}
__device__ __forceinline__ unsigned pack4f8(float a, float b, float c, float d) {
    int r = 0;
    r = __builtin_amdgcn_cvt_pk_fp8_f32(a, b, r, false);
    r = __builtin_amdgcn_cvt_pk_fp8_f32(c, d, r, true);
    return (unsigned)r;
}

// ---------------------------------------------------------------------------
// Fragment-major weights: flat i -> f=i>>9, l=(i>>3)&63, e=i&7; ks=f>>3, c=f&7;
// k = ks*32 + (l>>4)*8 + e; n = c*16 + (l&15).
// MFMA B-read: ((s16x8*)W)[f*64 + lane]  (lane-linear 1KB/instr, cacheable).
// ---------------------------------------------------------------------------
__global__ __launch_bounds__(256) void k_prep1(
    const float* __restrict__ W_h, const float* __restrict__ W_i,
    u16* __restrict__ wt_h, u16* __restrict__ wt_i)
{
    int i = blockIdx.x * 256 + threadIdx.x;
    if (i < Hh * Hh) {                       // wt_h: 32 frags
        int f = i >> 9, l = (i >> 3) & 63, e = i & 7;
        int ks = f >> 3, c = f & 7;
        int k = ks * 32 + (l >> 4) * 8 + e, n = c * 16 + (l & 15);
        wt_h[i] = f2bf(W_h[k * Hh + n]);
    } else {
        int j = i - Hh * Hh;
        if (j < 16 * 512) {                  // wt_i: 16 frags, k<41 else 0
            int f = j >> 9, l = (j >> 3) & 63, e = j & 7;
            int ks = f >> 3, c = f & 7;
            int k = ks * 32 + (l >> 4) * 8 + e, n = c * 16 + (l & 15);
            wt_i[j] = (k < 41) ? f2bf(W_i[k * Hh + n]) : (u16)0;
        }
    }
}

// wt_o: 48 frags; k<40 -> W_o[k][n]; 40..63 -> 0; 64..191 -> W_o[k-24][n]
__global__ __launch_bounds__(256) void k_prep2(
    const float* __restrict__ W_o, u16* __restrict__ wt_o)
{
    int i = blockIdx.x * 256 + threadIdx.x;
    if (i < 48 * 512) {
        int f = i >> 9, l = (i >> 3) & 63, e = i & 7;
        int ks = f >> 3, c = f & 7;
        int k = ks * 32 + (l >> 4) * 8 + e, n = c * 16 + (l & 15);
        u16 v = 0;
        if (k < FFn)                 v = f2bf(W_o[k * Hh + n]);
        else if (k >= 64 && k < 192) v = f2bf(W_o[(k - 24) * Hh + n]);
        wt_o[i] = v;
    }
}

// ---------------------------------------------------------------------------
// k_binput (MFMA, 512 thr): binput_bf = bf16(fedges @ W_i); msg = fp8(sigmoid)
// ---------------------------------------------------------------------------
union BinSmem {
    struct { u16 Wi[16 * 512]; u16 A[Hh * KI]; } s;  // 16384 + 18432 B
    float acc[Hh][ACCW];                             // 67584 B
};

__global__ __launch_bounds__(512, 4) void k_binput(
    const float* __restrict__ fedges, const u16* __restrict__ wt_i,
    u16* __restrict__ binput_bf, u8* __restrict__ msg)
{
    __shared__ BinSmem u;
    const int t = threadIdx.x;
    const int row0 = blockIdx.x * 128;
    const int nvalid = min(128, Ee - row0);

    {
        uint4 z = make_uint4(0, 0, 0, 0);
        for (int i = t; i < Hh * KI / 8; i += 512) {
            if (i < 1024) ((uint4*)u.s.Wi)[i] = ((const uint4*)wt_i)[i];
            ((uint4*)u.s.A)[i] = z;
        }
    }
    __syncthreads();
    for (int i = t; i < nvalid * 41; i += 512) {
        int r = i / 41, k = i - r * 41;
        u.s.A[r * KI + k] = f2bf(fedges[(size_t)row0 * 41 + i]);
    }
    __syncthreads();

    const int lane = t & 63, wid = t >> 6, l15 = lane & 15, l4 = lane >> 4;
    f32x4 acc[8];
    #pragma unroll
    for (int b = 0; b < 8; ++b) acc[b] = (f32x4){0.f, 0.f, 0.f, 0.f};

    #pragma unroll
    for (int ks = 0; ks < 2; ++ks) {
        s16x8 a = *(const s16x8*)&u.s.A[(wid * 16 + l15) * KI + ks * 32 + l4 * 8];
        #pragma unroll
        for (int c = 0; c < 8; ++c) {
            s16x8 b = ((const s16x8*)u.s.Wi)[(ks * 8 + c) * 64 + lane];
            acc[c] = __builtin_amdgcn_mfma_f32_16x16x32_bf16(a, b, acc[c], 0, 0, 0);
        }
    }
    __syncthreads();

    #pragma unroll
    for (int c = 0; c < 8; ++c)
        #pragma unroll
        for (int j = 0; j < 4; ++j)
            u.acc[wid * 16 + l4 * 4 + j][c * 16 + l15] = acc[c][j];
    __syncthreads();

    for (int i = t; i < Hh * 16; i += 512) {
        int row = i >> 4, seg = i & 15, grow = row0 + row;
        if (grow < Ee) {
            float4 a0 = *(const float4*)&u.acc[row][seg * 8];
            float4 a1 = *(const float4*)&u.acc[row][seg * 8 + 4];
            size_t o = (size_t)grow * Hh + seg * 8;
            uint4 bv;
            bv.x = pack2(a0.x, a0.y); bv.y = pack2(a0.z, a0.w);
            bv.z = pack2(a1.x, a1.y); bv.w = pack2(a1.z, a1.w);
            *(uint4*)&binput_bf[o] = bv;
            uint2 m;
            m.x = pack4f8(sigmoidf_(a0.x), sigmoidf_(a0.y),
                          sigmoidf_(a0.z), sigmoidf_(a0.w));
            m.y = pack4f8(sigmoidf_(a1.x), sigmoidf_(a1.y),
                          sigmoidf_(a1.z), sigmoidf_(a1.w));
            *(uint2*)&msg[o] = m;   // fp8 row = 128 B
        }
    }
}

// ---------------------------------------------------------------------------
// k_iter (MFMA, 512 thr, 128 rows): msg_out = fp8(sigmoid(binput + nei@W_h))
// Gather: 16 lanes/row x 8B fp8 -> one instruction covers a full 128B msg row
// (2 sectors).  Sums requantized bf16 into [row][KP] LDS; MFMA A from LDS,
// B from GLOBAL frag-major wt_h; two-64-row-half f32 epilogue via the union.
// LDS: union(N 34.8KB | acc 33.3KB) + sEG 4KB = 38.9 KB.
// ---------------------------------------------------------------------------
union IterSmem {
    u16 N[Hh * KP];             // 34816 B
    float acc[64][ACC2];        // 33280 B
};

__global__ __launch_bounds__(512, 6) void k_iter(
    const u8* __restrict__ msg_in, const int* __restrict__ egraph,
    const u16* __restrict__ wt_h, const u16* __restrict__ binput_bf,
    u8* __restrict__ msg_out)
{
    __shared__ IterSmem u;
    __shared__ int sEG[128 * NBn];
    const int t = threadIdx.x;
    const int row0 = blockIdx.x * 128;
    const int lane = t & 63, wid = t >> 6, l15 = lane & 15, l4 = lane >> 4;

    if (t < 256) {
        int r = row0 + (t >> 1);
        int4 v = make_int4(0, 0, 0, 0);
        if (r < Ee) v = ((const int4*)egraph)[r * 2 + (t & 1)];
        ((int4*)sEG)[t] = v;
    }
    __syncthreads();

    // gather: 16 lanes/row x 8B fp8; 32 rows per pass, 4 passes
    {
        const int s = t & 15, rl = t >> 4;
        #pragma unroll 2
        for (int pass = 0; pass < 4; ++pass) {
            int r = pass * 32 + rl;
            int grow = row0 + r;
            float a[8] = {0.f, 0.f, 0.f, 0.f, 0.f, 0.f, 0.f, 0.f};
            if (grow < Ee) {
                #pragma unroll
                for (int j = 0; j < NBn; ++j) {
                    int idx = sEG[r * NBn + j];
                    uint2 v = *(const uint2*)(msg_in + (size_t)idx * Hh + s * 8);
                    add8f8(a, v);
                }
            }
            uint4 o;
            o.x = pack2(a[0], a[1]); o.y = pack2(a[2], a[3]);
            o.z = pack2(a[4], a[5]); o.w = pack2(a[6], a[7]);
            *(uint4*)&u.N[r * KP + s * 8] = o;
        }
    }
    __syncthreads();

    // MFMA: A from LDS, B from global frag-major table
    f32x4 acc[8];
    #pragma unroll
    for (int b = 0; b < 8; ++b) acc[b] = (f32x4){0.f, 0.f, 0.f, 0.f};
    #pragma unroll
    for (int ks = 0; ks < 4; ++ks) {
        s16x8 a = *(const s16x8*)&u.N[(wid * 16 + l15) * KP + ks * 32 + l4 * 8];
        #pragma unroll
        for (int c = 0; c < 8; ++c) {
            s16x8 b = ((const s16x8*)wt_h)[(ks * 8 + c) * 64 + lane];
            acc[c] = __builtin_amdgcn_mfma_f32_16x16x32_bf16(a, b, acc[c], 0, 0, 0);
        }
    }
    __syncthreads();   // all LDS A-reads done -> union region reusable

    // epilogue: two 64-row halves through the union acc buffer
    #pragma unroll
    for (int h = 0; h < 2; ++h) {
        if ((wid >> 2) == h) {
            #pragma unroll
            for (int c = 0; c < 8; ++c)
                #pragma unroll
                for (int j = 0; j < 4; ++j)
                    u.acc[(wid & 3) * 16 + l4 * 4 + j][c * 16 + l15] = acc[c][j];
        }
        __syncthreads();
        for (int i = t; i < 64 * 16; i += 512) {
            int r = i >> 4, seg = i & 15;
            int g = row0 + h * 64 + r;
            if (g < Ee) {
                float4 a0 = *(const float4*)&u.acc[r][seg * 8];
                float4 a1 = *(const float4*)&u.acc[r][seg * 8 + 4];
                size_t o = (size_t)g * Hh + seg * 8;
                uint4 bv = *(const uint4*)&binput_bf[o];
                uint2 m;
                m.x = pack4f8(sigmoidf_(a0.x + bflo(bv.x)), sigmoidf_(a0.y + bfhi(bv.x)),
                              sigmoidf_(a0.z + bflo(bv.y)), sigmoidf_(a0.w + bfhi(bv.y)));
                m.y = pack4f8(sigmoidf_(a1.x + bflo(bv.z)), sigmoidf_(a1.y + bfhi(bv.z)),
                              sigmoidf_(a1.z + bflo(bv.w)), sigmoidf_(a1.w + bfhi(bv.w)));
                *(uint2*)&msg_out[o] = m;
            }
        }
        __syncthreads();
    }
}

// ---------------------------------------------------------------------------
// k_final (MFMA, 256 thr, 64 rows): hidden = bf16(sigmoid([feat|0|nei]@W_o+b))
// fp8 gather; B from GLOBAL frag-major wt_o.
// ---------------------------------------------------------------------------
union FinSmem {
    u16 A[64 * KO];         // 25600 B
    float acc[64][ACCW];    // 33792 B
};

__global__ __launch_bounds__(256, 4) void k_final(
    const u8* __restrict__ msg_in, const int* __restrict__ agraph,
    const float* __restrict__ features, const u16* __restrict__ wt_o,
    const float* __restrict__ b_o, u16* __restrict__ hidden)
{
    __shared__ FinSmem u;
    __shared__ int sAG[64 * NBn];   // 2048 B
    __shared__ float sBias[Hh];     // 512 B
    const int t = threadIdx.x;
    const int row0 = blockIdx.x * 64;
    const int nvalid = min(64, Nn - row0);

    {
        uint4 z = make_uint4(0, 0, 0, 0);
        for (int i = t; i < 64 * KO / 8; i += 256) ((uint4*)u.A)[i] = z;
    }
    if (t < 128) {
        int r = row0 + (t >> 1);
        int4 v = make_int4(0, 0, 0, 0);
        if (r < Nn) v = ((const int4*)agraph)[r * 2 + (t & 1)];
        ((int4*)sAG)[t] = v;
    }
    if (t < Hh / 4) ((float4*)sBias)[t] = ((const float4*)b_o)[t];
    __syncthreads();

    for (int i = t; i < nvalid * FFn; i += 256) {
        int r = i / FFn, k = i - r * FFn;
        u.A[r * KO + k] = f2bf(features[(size_t)row0 * FFn + i]);
    }
    {
        const int s = t & 15, rl = t >> 4;
        #pragma unroll 2
        for (int pass = 0; pass < 4; ++pass) {
            int r = pass * 16 + rl;
            int grow = row0 + r;
            float a[8] = {0.f, 0.f, 0.f, 0.f, 0.f, 0.f, 0.f, 0.f};
            if (grow < Nn) {
                #pragma unroll
                for (int j = 0; j < NBn; ++j) {
                    int idx = sAG[r * NBn + j];
                    uint2 v = *(const uint2*)(msg_in + (size_t)idx * Hh + s * 8);
                    add8f8(a, v);
                }
            }
            uint4 o;
            o.x = pack2(a[0], a[1]); o.y = pack2(a[2], a[3]);
            o.z = pack2(a[4], a[5]); o.w = pack2(a[6], a[7]);
            *(uint4*)&u.A[r * KO + 64 + s * 8] = o;
        }
    }
    __syncthreads();

    const int lane = t & 63, wid = t >> 6, l15 = lane & 15, l4 = lane >> 4;
    f32x4 acc[8];
    #pragma unroll
    for (int b = 0; b < 8; ++b) acc[b] = (f32x4){0.f, 0.f, 0.f, 0.f};

    #pragma unroll
    for (int ks = 0; ks < 6; ++ks) {
        s16x8 a = *(const s16x8*)&u.A[(wid * 16 + l15) * KO + ks * 32 + l4 * 8];
        #pragma unroll
        for (int c = 0; c < 8; ++c) {
            s16x8 b = ((const s16x8*)wt_o)[(ks * 8 + c) * 64 + lane];
            acc[c] = __builtin_amdgcn_mfma_f32_16x16x32_bf16(a, b, acc[c], 0, 0, 0);
        }
    }
    __syncthreads();   // A reads done -> union reusable

    #pragma unroll
    for (int c = 0; c < 8; ++c)
        #pragma unroll
        for (int j = 0; j < 4; ++j)
            u.acc[wid * 16 + l4 * 4 + j][c * 16 + l15] = acc[c][j];
    __syncthreads();

    for (int i = t; i < 64 * 16; i += 256) {
        int r = i >> 4, seg = i & 15, g = row0 + r;
        if (g < Nn) {
            float4 a0 = *(const float4*)&u.acc[r][seg * 8];
            float4 a1 = *(const float4*)&u.acc[r][seg * 8 + 4];
            const float* bb = &sBias[seg * 8];
            uint4 m;
            m.x = pack2(sigmoidf_(a0.x + bb[0]), sigmoidf_(a0.y + bb[1]));
            m.y = pack2(sigmoidf_(a0.z + bb[2]), sigmoidf_(a0.w + bb[3]));
            m.z = pack2(sigmoidf_(a1.x + bb[4]), sigmoidf_(a1.y + bb[5]));
            m.w = pack2(sigmoidf_(a1.z + bb[6]), sigmoidf_(a1.w + bb[7]));
            *(uint4*)&hidden[(size_t)g * Hh + seg * 8] = m;
        }
    }
}

// ---------------------------------------------------------------------------
// k_pool: segment mean over bf16 hidden. One block (128 threads) / molecule.
// ---------------------------------------------------------------------------
__global__ __launch_bounds__(128) void k_pool(
    const u16* __restrict__ hidden, const int* __restrict__ scope,
    float* __restrict__ out)
{
    const int b = blockIdx.x;
    const int t = threadIdx.x;
    const int start = scope[b * 2 + 0];
    const int len   = scope[b * 2 + 1];
    float acc = 0.f;
    for (int i = 0; i < len; ++i)
        acc += bf1(hidden[(size_t)(start + i) * Hh + t]);
    out[(size_t)b * Hh + t] = acc / (float)len;
}

// ---------------------------------------------------------------------------
extern "C" void kernel_launch(void* const* d_in, const int* in_sizes, int n_in,
                              void* d_out, int out_size, void* d_ws, size_t ws_size,
                              hipStream_t stream)
{
    const float* features = (const float*)d_in[0];
    const float* fedges   = (const float*)d_in[1];
    const int*   agraph   = (const int*)d_in[2];
    const int*   egraph   = (const int*)d_in[3];
    const int*   scope    = (const int*)d_in[4];
    const float* W_i      = (const float*)d_in[5];
    const float* W_h      = (const float*)d_in[6];
    const float* W_o      = (const float*)d_in[7];
    const float* b_o      = (const float*)d_in[8];
    float* out = (float*)d_out;

    // Workspace: binput bf16[E*128] | msg0 fp8[E*128] | msg1 fp8[E*128] | wt_h.
    // wt_i parks in msg1 (consumed by k_binput before iter0 writes msg1);
    // wt_o parks in binput region (prepped after the last k_iter);
    // hidden (bf16, 12.8 MB) lives in the final free fp8 plane (msg0, 19.2 MB).
    const size_t plane = (size_t)Ee * Hh;    // elements per plane
    u16* binput_bf = (u16*)d_ws;
    u8*  msg0 = (u8*)(binput_bf + plane);
    u8*  msg1 = msg0 + plane;
    u16* wt_h = (u16*)(msg1 + plane);        // 16384 u16
    u16* wt_i = (u16*)msg1;                  // 8192 u16 (parked)
    u16* wt_o = binput_bf;                   // 24576 u16 (parked, used last)

    k_prep1<<<(Hh * Hh + 16 * 512 + 255) / 256, 256, 0, stream>>>(W_h, W_i, wt_h, wt_i);

    const int eblocks = (Ee + 127) / 128;
    k_binput<<<eblocks, 512, 0, stream>>>(fedges, wt_i, binput_bf, msg0);

    u8* src = msg0;
    u8* dst = msg1;
    for (int d = 0; d < ITERS; ++d) {
        k_iter<<<eblocks, 512, 0, stream>>>(src, egraph, wt_h, binput_bf, dst);
        u8* tmp = src; src = dst; dst = tmp;
    }
    // final message in `src` (= msg1); binput now dead -> prep wt_o there.
    k_prep2<<<(48 * 512) / 256, 256, 0, stream>>>(W_o, wt_o);

    u16* hidden = (u16*)dst;   // = msg0 region (free, 19.2 MB >= 12.8 MB)
    const int nblocks = (Nn + 63) / 64;
    k_final<<<nblocks, 256, 0, stream>>>(src, agraph, features, wt_o, b_o, hidden);

    k_pool<<<Bm, 128, 0, stream>>>(hidden, scope, out);
}